// Round 1
// baseline (1136.921 us; speedup 1.0000x reference)
//
#include <hip/hip_runtime.h>
#include <stdint.h>

// Problem constants (fixed by the reference)
#define M_DIM 8192
#define K_DIM 4096
#define N_DIM 11008
#define KP_DIM 512     // K/8 packed int32 rows

// Workspace layout (bytes):
//   A_pre: M*K bf16 in fragment order  = 67,108,864
//   B_pre: K*N bf16 in fragment order  = 90,177,536
#define A_PRE_BYTES (67108864ull)
#define B_PRE_BYTES (90177536ull)
#define WS_NEEDED   (A_PRE_BYTES + B_PRE_BYTES)

typedef __attribute__((ext_vector_type(8))) short bf16x8;   // MFMA A/B frag (4 VGPRs)
typedef __attribute__((ext_vector_type(4))) float f32x4;    // MFMA C/D frag

// fp32 -> bf16 (round-to-nearest, ties up), packed pair
__device__ __forceinline__ uint32_t pack2_bf16(float lo, float hi) {
    uint32_t ulo = (__float_as_uint(lo) + 0x8000u) >> 16;
    uint32_t uhi = (__float_as_uint(hi) + 0x8000u) & 0xFFFF0000u;
    return uhi | ulo;
}

// One packed int32 (8 nibbles along K) -> 8 dequantized bf16 (one 16B frag chunk).
// 0x43000000|(nib<<16) is the fp32 bit pattern of (128+nib); w=(128+q)*s + b, b=-(128+z)*s.
__device__ __forceinline__ uint4 dequant_word(uint32_t w, float s, float b) {
    const uint32_t MG = 0x43000000u, MK = 0x000F0000u;
    float f0 = __uint_as_float(((w << 16) & MK) | MG);
    float f1 = __uint_as_float(((w << 12) & MK) | MG);
    float f2 = __uint_as_float(((w <<  8) & MK) | MG);
    float f3 = __uint_as_float(((w <<  4) & MK) | MG);
    float f4 = __uint_as_float(( w        & MK) | MG);
    float f5 = __uint_as_float(((w >>  4) & MK) | MG);
    float f6 = __uint_as_float(((w >>  8) & MK) | MG);
    float f7 = __uint_as_float(((w >> 12) & MK) | MG);
    uint4 o;
    o.x = pack2_bf16(fmaf(f0, s, b), fmaf(f1, s, b));
    o.y = pack2_bf16(fmaf(f2, s, b), fmaf(f3, s, b));
    o.z = pack2_bf16(fmaf(f4, s, b), fmaf(f5, s, b));
    o.w = pack2_bf16(fmaf(f6, s, b), fmaf(f7, s, b));
    return o;
}

// ---------------- Fragment-order layout (256-tile, BK=32) ----------------
// 16B chunk index for A: ((mblk256*128 + kt)*16 + m16)*64 + lane
//   lane = (q<<4)|(row&15), q = (k&31)>>3, m16 = (row>>4)&15, kt = k>>5
// Same for B with n in place of row. Per K-tile the region is 16 KB contiguous
// -> linear global_load_lds staging, stride-1 conflict-free ds_read_b128.

// ---------------- Prepass 1: x fp32 -> A_pre (dst-major, stride-1 writes) ----------------
// grid 16384 x 256: thread = dst chunk; reads 32B of one row (128B segments per wave)
__global__ void conv_x(const float* __restrict__ x, uint32_t* __restrict__ Apre) {
    const size_t d = (size_t)blockIdx.x * 256 + threadIdx.x;  // dst chunk 0..4194303
    const int lane = (int)(d & 63);
    const int m16  = (int)((d >> 6) & 15);
    const int kt   = (int)((d >> 10) & 127);
    const int mblk = (int)(d >> 17);
    const int row  = mblk * 256 + m16 * 16 + (lane & 15);
    const int k    = kt * 32 + (lane >> 4) * 8;
    const float4* p = reinterpret_cast<const float4*>(x + (size_t)row * K_DIM + k);
    float4 v0 = p[0], v1 = p[1];
    uint4 o;
    o.x = pack2_bf16(v0.x, v0.y);
    o.y = pack2_bf16(v0.z, v0.w);
    o.z = pack2_bf16(v1.x, v1.y);
    o.w = pack2_bf16(v1.z, v1.w);
    *reinterpret_cast<uint4*>(Apre + d * 4) = o;
}

// ---------------- Prepass 2: W_q int4 -> B_pre (dst-major, stride-1 writes) ----------------
// grid 22016 x 256: thread = dst chunk = one packed word (kp, n)
__global__ void dequant_w(const int* __restrict__ Wq, const float* __restrict__ scales,
                          const float* __restrict__ zeros, uint32_t* __restrict__ Bpre) {
    const size_t d = (size_t)blockIdx.x * 256 + threadIdx.x;  // dst chunk 0..5636095
    const int lane = (int)(d & 63);
    const int n16  = (int)((d >> 6) & 15);
    const int kt   = (int)((d >> 10) & 127);
    const int nblk = (int)(d >> 17);
    const int n    = nblk * 256 + n16 * 16 + (lane & 15);
    const int kp   = kt * 4 + (lane >> 4);
    const uint32_t w = (uint32_t)Wq[(size_t)kp * N_DIM + n];
    const int g = kp >> 4;                            // k/128
    const float s = scales[(size_t)g * N_DIM + n];
    const float z = zeros[(size_t)g * N_DIM + n];
    const float b = -(128.0f + z) * s;
    uint4 o = dequant_word(w, s, b);
    *reinterpret_cast<uint4*>(Bpre + d * 4) = o;
}

// ---------------- Main GEMM: 256x256 tile, 8 waves, 4-buffer counted-vmcnt pipeline ----------
#define GLD16(g, l) __builtin_amdgcn_global_load_lds(                        \
    (const __attribute__((address_space(1))) uint32_t*)(g),                  \
    (__attribute__((address_space(3))) uint32_t*)(l), 16, 0, 0)

#define GRID_BLKS 1376   // (8192/256)*(11008/256) = 32*43, divisible by 8

__global__ __launch_bounds__(512, 2)
void gemm_pre(const uint32_t* __restrict__ Apre, const uint32_t* __restrict__ Bpre,
              float* __restrict__ out) {
    // 4 K-tile buffers x (A 16KB + B 16KB) = 128 KB
    __shared__ uint32_t lds[32768];

    const int tid  = threadIdx.x;
    const int lane = tid & 63;
    const int wv   = tid >> 6;        // 0..7
    const int wm   = wv >> 2;         // 0..1 : 128 rows each
    const int wn   = wv & 3;          // 0..3 : 64 cols each

    // XCD-aware bijective swizzle (1376 % 8 == 0): consecutive swz share B panel
    const int bid  = blockIdx.x;
    const int swz  = (bid & 7) * (GRID_BLKS / 8) + (bid >> 3);
    const int mblk = swz & 31;        // 0..31
    const int nblk = swz >> 5;        // 0..42

    // per-lane global staging pointers (u32 words); per K-tile stride = 4096 words (16 KB)
    const uint32_t* ag = Apre + (size_t)mblk * 524288 + (size_t)tid * 4;
    const uint32_t* bg = Bpre + (size_t)nblk * 524288 + (size_t)tid * 4;

    f32x4 acc[8][4];
#pragma unroll
    for (int mt = 0; mt < 8; ++mt)
#pragma unroll
        for (int nt = 0; nt < 4; ++nt)
            acc[mt][nt] = (f32x4){0.f, 0.f, 0.f, 0.f};

    // ---- prologue: stage tiles 0,1,2 (12 loads), then tile 0 is ready after vmcnt(8)
#pragma unroll
    for (int t = 0; t < 3; ++t) {
        GLD16(ag + t * 4096,        &lds[t * 8192 + wv * 256]);
        GLD16(ag + t * 4096 + 2048, &lds[t * 8192 + 2048 + wv * 256]);
        GLD16(bg + t * 4096,        &lds[t * 8192 + 4096 + wv * 256]);
        GLD16(bg + t * 4096 + 2048, &lds[t * 8192 + 6144 + wv * 256]);
    }
    asm volatile("s_waitcnt vmcnt(8)" ::: "memory");
    __builtin_amdgcn_s_barrier();

    for (int t = 0; t < 128; ++t) {
        const int buf = t & 3;
        const uint32_t* Ab = &lds[buf * 8192 + wm * 2048 + lane * 4];
        const uint32_t* Bb = &lds[buf * 8192 + 4096 + wn * 1024 + lane * 4];

        // ---- phase 1: read all 8 A-frags + B-frags 0,1; issue A(t+3); MFMA Q1
        bf16x8 af[8], bfr[4];
#pragma unroll
        for (int mt = 0; mt < 8; ++mt)
            af[mt] = *reinterpret_cast<const bf16x8*>(Ab + mt * 256);
        bfr[0] = *reinterpret_cast<const bf16x8*>(Bb);
        bfr[1] = *reinterpret_cast<const bf16x8*>(Bb + 256);
        if (t < 125) {
            const int tn = t + 3, bn = tn & 3;
            GLD16(ag + tn * 4096,        &lds[bn * 8192 + wv * 256]);
            GLD16(ag + tn * 4096 + 2048, &lds[bn * 8192 + 2048 + wv * 256]);
        }
        __builtin_amdgcn_s_barrier();
        __builtin_amdgcn_s_setprio(1);
#pragma unroll
        for (int mt = 0; mt < 8; ++mt)
#pragma unroll
            for (int nt = 0; nt < 2; ++nt)
                acc[mt][nt] = __builtin_amdgcn_mfma_f32_16x16x32_bf16(
                    af[mt], bfr[nt], acc[mt][nt], 0, 0, 0);
        __builtin_amdgcn_s_setprio(0);
        __builtin_amdgcn_s_barrier();

        // ---- phase 2: read B-frags 2,3; issue B(t+3); MFMA Q2; boundary wait
        bfr[2] = *reinterpret_cast<const bf16x8*>(Bb + 512);
        bfr[3] = *reinterpret_cast<const bf16x8*>(Bb + 768);
        if (t < 125) {
            const int tn = t + 3, bn = tn & 3;
            GLD16(bg + tn * 4096,        &lds[bn * 8192 + 4096 + wv * 256]);
            GLD16(bg + tn * 4096 + 2048, &lds[bn * 8192 + 6144 + wv * 256]);
        }
        __builtin_amdgcn_s_barrier();
        __builtin_amdgcn_s_setprio(1);
#pragma unroll
        for (int mt = 0; mt < 8; ++mt)
#pragma unroll
            for (int nt = 2; nt < 4; ++nt)
                acc[mt][nt] = __builtin_amdgcn_mfma_f32_16x16x32_bf16(
                    af[mt], bfr[nt], acc[mt][nt], 0, 0, 0);
        __builtin_amdgcn_s_setprio(0);
        // counted boundary wait: tile t+1 fully landed; never drains until the tail
        if (t < 125)       asm volatile("s_waitcnt vmcnt(8)" ::: "memory");
        else if (t == 125) asm volatile("s_waitcnt vmcnt(4)" ::: "memory");
        else if (t == 126) asm volatile("s_waitcnt vmcnt(0)" ::: "memory");
        __builtin_amdgcn_s_barrier();
    }

    // epilogue: C/D layout col = lane&15, row = (lane>>4)*4 + reg  [m89/m91]
    const int colc = lane & 15, qr = lane >> 4;
#pragma unroll
    for (int mt = 0; mt < 8; ++mt) {
#pragma unroll
        for (int nt = 0; nt < 4; ++nt) {
            int row0 = mblk * 256 + wm * 128 + mt * 16 + qr * 4;
            int c    = nblk * 256 + wn * 64 + nt * 16 + colc;
#pragma unroll
            for (int i = 0; i < 4; ++i)
                out[(size_t)(row0 + i) * N_DIM + c] = acc[mt][nt][i];
        }
    }
}

// ---------------- Fallback: round-1 fused kernel (used only if ws too small) ----------------
__global__ __launch_bounds__(256, 2)
void qgemm_fused(const float* __restrict__ x, const int* __restrict__ Wq,
                 const float* __restrict__ scales, const float* __restrict__ zeros,
                 float* __restrict__ out) {
    __shared__ uint32_t As[4096];
    __shared__ uint32_t Bs[4096];

    const int tid  = threadIdx.x;
    const int lane = tid & 63;
    const int wv   = tid >> 6;
    const int wm   = wv >> 1, wn = wv & 1;
    const int m0 = blockIdx.x * 128;
    const int n0 = blockIdx.y * 128;
    const int bc  = tid & 127;
    const int brh = tid >> 7;

    int a_row[4], a_col[4], a_dst[4];
#pragma unroll
    for (int j = 0; j < 4; ++j) {
        int sl  = tid + 256 * j;
        int blk = sl >> 6;
        int ln  = sl & 63;
        int mt  = blk >> 1, ks = blk & 1;
        a_row[j] = m0 + mt * 16 + (ln & 15);
        a_col[j] = ks * 32 + (ln >> 4) * 8;
        a_dst[j] = blk * 256 + ln * 4;
    }

    f32x4 acc[4][4];
#pragma unroll
    for (int mt = 0; mt < 4; ++mt)
#pragma unroll
        for (int nt = 0; nt < 4; ++nt)
            acc[mt][nt] = (f32x4){0.f, 0.f, 0.f, 0.f};

    float4   pa[4][2];
    uint32_t pw[4];
    float    s_raw, z_raw;
#pragma unroll
    for (int j = 0; j < 4; ++j) {
        const float4* p = reinterpret_cast<const float4*>(
            x + (size_t)a_row[j] * K_DIM + a_col[j]);
        pa[j][0] = p[0];
        pa[j][1] = p[1];
    }
#pragma unroll
    for (int j = 0; j < 4; ++j) {
        int r = brh * 4 + j;
        pw[j] = (uint32_t)Wq[(size_t)r * N_DIM + n0 + bc];
    }
    s_raw = scales[n0 + bc];
    z_raw = zeros[n0 + bc];

    float sv = 0.f, bv = 0.f;

    for (int kk = 0; kk < K_DIM; kk += 64) {
        if ((kk & 127) == 0) {
            sv = s_raw;
            bv = -(128.0f + z_raw) * s_raw;
        }
#pragma unroll
        for (int j = 0; j < 4; ++j) {
            uint4 o;
            o.x = pack2_bf16(pa[j][0].x, pa[j][0].y);
            o.y = pack2_bf16(pa[j][0].z, pa[j][0].w);
            o.z = pack2_bf16(pa[j][1].x, pa[j][1].y);
            o.w = pack2_bf16(pa[j][1].z, pa[j][1].w);
            *reinterpret_cast<uint4*>(&As[a_dst[j]]) = o;
        }
#pragma unroll
        for (int j = 0; j < 4; ++j) {
            int r  = brh * 4 + j;
            uint4 o = dequant_word(pw[j], sv, bv);
            int ks  = r >> 2, q = r & 3;
            int blk = ((bc >> 4) << 1) | ks;
            *reinterpret_cast<uint4*>(&Bs[blk * 256 + (q * 16 + (bc & 15)) * 4]) = o;
        }
        __syncthreads();

        int kn = kk + 64;
        if (kn < K_DIM) {
#pragma unroll
            for (int j = 0; j < 4; ++j) {
                const float4* p = reinterpret_cast<const float4*>(
                    x + (size_t)a_row[j] * K_DIM + kn + a_col[j]);
                pa[j][0] = p[0];
                pa[j][1] = p[1];
            }
            int kp0 = kn >> 3;
#pragma unroll
            for (int j = 0; j < 4; ++j) {
                int r = brh * 4 + j;
                pw[j] = (uint32_t)Wq[(size_t)(kp0 + r) * N_DIM + n0 + bc];
            }
            if ((kn & 127) == 0) {
                int g = kn >> 7;
                s_raw = scales[(size_t)g * N_DIM + n0 + bc];
                z_raw = zeros[(size_t)g * N_DIM + n0 + bc];
            }
        }

#pragma unroll
        for (int ks = 0; ks < 2; ++ks) {
            bf16x8 af[4], bfr[4];
#pragma unroll
            for (int mt = 0; mt < 4; ++mt)
                af[mt] = *reinterpret_cast<const bf16x8*>(
                    &As[(((wm * 4 + mt) << 1) | ks) * 256 + lane * 4]);
#pragma unroll
            for (int nt = 0; nt < 4; ++nt)
                bfr[nt] = *reinterpret_cast<const bf16x8*>(
                    &Bs[(((wn * 4 + nt) << 1) | ks) * 256 + lane * 4]);
#pragma unroll
            for (int mt = 0; mt < 4; ++mt)
#pragma unroll
                for (int nt = 0; nt < 4; ++nt)
                    acc[mt][nt] = __builtin_amdgcn_mfma_f32_16x16x32_bf16(
                        af[mt], bfr[nt], acc[mt][nt], 0, 0, 0);
        }
        __syncthreads();
    }

    const int colc = lane & 15, qr = lane >> 4;
#pragma unroll
    for (int mt = 0; mt < 4; ++mt) {
#pragma unroll
        for (int nt = 0; nt < 4; ++nt) {
            int row0 = m0 + (wm * 4 + mt) * 16 + qr * 4;
            int c    = n0 + (wn * 4 + nt) * 16 + colc;
#pragma unroll
            for (int i = 0; i < 4; ++i)
                out[(size_t)(row0 + i) * N_DIM + c] = acc[mt][nt][i];
        }
    }
}

extern "C" void kernel_launch(void* const* d_in, const int* in_sizes, int n_in,
                              void* d_out, int out_size, void* d_ws, size_t ws_size,
                              hipStream_t stream) {
    const float* x      = (const float*)d_in[0];
    const int*   Wq     = (const int*)d_in[1];
    const float* scales = (const float*)d_in[2];
    const float* zeros  = (const float*)d_in[3];
    float*       out    = (float*)d_out;

    if (ws_size >= WS_NEEDED) {
        uint32_t* Apre = (uint32_t*)d_ws;
        uint32_t* Bpre = (uint32_t*)((char*)d_ws + A_PRE_BYTES);
        conv_x<<<dim3(16384), dim3(256), 0, stream>>>(x, Apre);
        dequant_w<<<dim3(22016), dim3(256), 0, stream>>>(Wq, scales, zeros, Bpre);
        gemm_pre<<<dim3(GRID_BLKS), dim3(512), 0, stream>>>(Apre, Bpre, out);
    } else {
        qgemm_fused<<<dim3(M_DIM / 128, N_DIM / 128), dim3(256), 0, stream>>>(
            x, Wq, scales, zeros, out);
    }
}

// Round 2
// 1063.128 us; speedup vs baseline: 1.0694x; 1.0694x over previous
//
#include <hip/hip_runtime.h>
#include <stdint.h>

// Problem constants (fixed by the reference)
#define M_DIM 8192
#define K_DIM 4096
#define N_DIM 11008
#define KP_DIM 512     // K/8 packed int32 rows
// group size 128 along K -> group g = kp/16

// Workspace layout (bytes):
//   A_pre: M*K bf16 in fragment order  = 67,108,864
//   B_pre: K*N bf16 in fragment order  = 90,177,536
#define A_PRE_BYTES (67108864ull)
#define B_PRE_BYTES (90177536ull)
#define WS_NEEDED   (A_PRE_BYTES + B_PRE_BYTES)

typedef __attribute__((ext_vector_type(8))) short bf16x8;   // MFMA A/B frag (4 VGPRs)
typedef __attribute__((ext_vector_type(4))) float f32x4;    // MFMA C/D frag

// fp32 -> bf16 (round-to-nearest, ties up), packed pair
__device__ __forceinline__ uint32_t pack2_bf16(float lo, float hi) {
    uint32_t ulo = (__float_as_uint(lo) + 0x8000u) >> 16;
    uint32_t uhi = (__float_as_uint(hi) + 0x8000u) & 0xFFFF0000u;
    return uhi | ulo;
}

// One packed int32 (8 nibbles along K) -> 8 dequantized bf16 (one 16B frag chunk).
// 0x43000000|(nib<<16) is the fp32 bit pattern of (128+nib); w=(128+q)*s + b, b=-(128+z)*s.
__device__ __forceinline__ uint4 dequant_word(uint32_t w, float s, float b) {
    const uint32_t MG = 0x43000000u, MK = 0x000F0000u;
    float f0 = __uint_as_float(((w << 16) & MK) | MG);
    float f1 = __uint_as_float(((w << 12) & MK) | MG);
    float f2 = __uint_as_float(((w <<  8) & MK) | MG);
    float f3 = __uint_as_float(((w <<  4) & MK) | MG);
    float f4 = __uint_as_float(( w        & MK) | MG);
    float f5 = __uint_as_float(((w >>  4) & MK) | MG);
    float f6 = __uint_as_float(((w >>  8) & MK) | MG);
    float f7 = __uint_as_float(((w >> 12) & MK) | MG);
    uint4 o;
    o.x = pack2_bf16(fmaf(f0, s, b), fmaf(f1, s, b));
    o.y = pack2_bf16(fmaf(f2, s, b), fmaf(f3, s, b));
    o.z = pack2_bf16(fmaf(f4, s, b), fmaf(f5, s, b));
    o.w = pack2_bf16(fmaf(f6, s, b), fmaf(f7, s, b));
    return o;
}

// Fragment-order addressing (round-0 layout, shared by prepasses and GEMM):
//   16B chunk index = ((blk128 * 64 + k_blk) * 16 + mt*2 + ks) * 64 + lane
//   lane = (q << 4) | (row_or_col & 15),  q = (k % 32) / 8,  ks = (k % 64) / 32
// GEMM stage (blk128, k_blk) is then 16 KB contiguous -> global_load_lds dwordx4
// with wave-uniform LDS base + lane*16, perfectly coalesced global reads.

// ---------------- Prepass 1: x fp32 -> A_pre (LDS transpose, both sides coalesced) ----
// grid (512, 4) x 256: block = 16 rows x 1024 k.
// Reads: 1 KB contiguous per wave-instr. Writes: 1 KB contiguous per wave-instr.
__global__ __launch_bounds__(256)
void conv_x(const float* __restrict__ x, uint32_t* __restrict__ Apre) {
    __shared__ uint32_t lds[8256];            // [16 rows][516 u32] bf16, 33 KB (pad->no conflicts)
    const int t  = threadIdx.x;
    const int w  = t >> 6;                    // wave 0..3
    const int ln = t & 63;
    const int r0 = blockIdx.x * 16;
    const int mblk = r0 >> 7, mt = (r0 >> 4) & 7;   // fixed per block
    const int k0  = blockIdx.y * 1024;
    const int kb0 = blockIdx.y * 16;          // first 64-k block

    // load + convert: wave reads one row's 4 KB as 4 x (64 lanes x 16 B)
#pragma unroll
    for (int j = 0; j < 4; ++j) {
        const int rl = w + j * 4;             // row_local 0..15
        const float4* rp = reinterpret_cast<const float4*>(
            x + (size_t)(r0 + rl) * K_DIM + k0);
#pragma unroll
        for (int i = 0; i < 4; ++i) {
            float4 v = rp[ln + i * 64];
            uint32_t* p = &lds[rl * 516 + (ln + i * 64) * 2];
            p[0] = pack2_bf16(v.x, v.y);
            p[1] = pack2_bf16(v.z, v.w);
        }
    }
    __syncthreads();

    // write out fragment order: one (kblk, ks) slice = 1 KB contiguous per wave-instr
    const int lr = ln & 15, q = ln >> 4;
#pragma unroll
    for (int it = 0; it < 8; ++it) {
        const int idx = it * 4 + w;           // 0..31
        const int kbl = idx >> 1, ks = idx & 1;
        const uint4 v = *reinterpret_cast<const uint4*>(
            &lds[lr * 516 + kbl * 32 + ks * 16 + q * 4]);
        const size_t d = (((size_t)mblk * 64 + kb0 + kbl) * 16 + mt * 2 + ks) * 64 + ln;
        *reinterpret_cast<uint4*>(Apre + d * 4) = v;
    }
}

// ---------------- Prepass 2: W_q int4 -> B_pre (LDS transpose, both sides coalesced) --
// grid (43, 128) x 256: block = 4 kp x 256 n.
// Reads: 256 B contiguous per wave-instr along n. Writes: 1 KB contiguous per instr.
__global__ __launch_bounds__(256)
void dequant_w(const int* __restrict__ Wq, const float* __restrict__ scales,
               const float* __restrict__ zeros, uint32_t* __restrict__ Bpre) {
    __shared__ uint32_t lds[5120];            // [256 n][5 uint4] = 20 KB (stride 5 -> no conflicts)
    const int t  = threadIdx.x;
    const int w  = t >> 6;                    // wave = kp sub-row 0..3 (= q)
    const int ln = t & 63;
    const int n0  = blockIdx.x * 256;
    const int kp0 = blockIdx.y * 4;
    const int kp  = kp0 + w;
    const int g   = kp0 >> 4;                 // fixed per block (4 kp within one group)
    const int kblk = kp0 >> 3, ks = (kp0 >> 2) & 1;  // fixed per block
    const int nb0 = n0 >> 7;                  // block spans n_blk nb0, nb0+1

#pragma unroll
    for (int i = 0; i < 4; ++i) {
        const int n = n0 + ln + i * 64;
        const uint32_t wq = (uint32_t)Wq[(size_t)kp * N_DIM + n];
        const float s = scales[(size_t)g * N_DIM + n];
        const float z = zeros[(size_t)g * N_DIM + n];
        uint4 o = dequant_word(wq, s, -(128.0f + z) * s);
        const int nl = ln + i * 64;
        *reinterpret_cast<uint4*>(&lds[(nl * 5 + w) * 4]) = o;
    }
    __syncthreads();

    const int lr = ln & 15, q = ln >> 4;
#pragma unroll
    for (int it = 0; it < 4; ++it) {
        const int idx = it * 4 + w;           // 0..15
        const int nh = idx >> 3, nt = idx & 7;
        const int nl = nh * 128 + nt * 16 + lr;
        const uint4 v = *reinterpret_cast<const uint4*>(&lds[(nl * 5 + q) * 4]);
        const size_t d = (((size_t)(nb0 + nh) * 64 + kblk) * 16 + nt * 2 + ks) * 64 + ln;
        *reinterpret_cast<uint4*>(Bpre + d * 4) = v;
    }
}

// ---------------- Main GEMM: pure bf16, m97 pattern (round-0 proven: 642 us) ----------
#define GLD16(g, l) __builtin_amdgcn_global_load_lds(                        \
    (const __attribute__((address_space(1))) uint32_t*)(g),                  \
    (__attribute__((address_space(3))) uint32_t*)(l), 16, 0, 0)

__global__ __launch_bounds__(256, 2)
void gemm_pre(const uint32_t* __restrict__ Apre, const uint32_t* __restrict__ Bpre,
              float* __restrict__ out) {
    __shared__ uint32_t As[4096];   // 16 KB, fragment order: 16 blocks of 1 KB
    __shared__ uint32_t Bs[4096];

    const int tid  = threadIdx.x;
    const int lane = tid & 63;
    const int wv   = tid >> 6;
    const int wm   = wv >> 1, wn = wv & 1;
    const int m_blk = blockIdx.x, n_blk = blockIdx.y;

    // wave wv stages A-blocks and B-blocks wv*4 .. wv*4+3 each stage
    const uint32_t* ag = Apre + ((size_t)m_blk * 64 * 16 + wv * 4) * 256 + lane * 4;
    const uint32_t* bg = Bpre + ((size_t)n_blk * 64 * 16 + wv * 4) * 256 + lane * 4;
    uint32_t* al = &As[(wv * 4) * 256];   // wave-uniform LDS bases
    uint32_t* bl = &Bs[(wv * 4) * 256];

    f32x4 acc[4][4];
#pragma unroll
    for (int mt = 0; mt < 4; ++mt)
#pragma unroll
        for (int nt = 0; nt < 4; ++nt)
            acc[mt][nt] = (f32x4){0.f, 0.f, 0.f, 0.f};

    for (int kb = 0; kb < 64; ++kb) {
#pragma unroll
        for (int i = 0; i < 4; ++i) {
            GLD16(ag + i * 256, al + i * 256);
            GLD16(bg + i * 256, bl + i * 256);
        }
        ag += 4096;   // next 16 KB stage
        bg += 4096;
        __syncthreads();

#pragma unroll
        for (int ks = 0; ks < 2; ++ks) {
            bf16x8 af[4], bfr[4];
#pragma unroll
            for (int mt = 0; mt < 4; ++mt)
                af[mt] = *reinterpret_cast<const bf16x8*>(
                    &As[(((wm * 4 + mt) << 1) | ks) * 256 + lane * 4]);
#pragma unroll
            for (int nt = 0; nt < 4; ++nt)
                bfr[nt] = *reinterpret_cast<const bf16x8*>(
                    &Bs[(((wn * 4 + nt) << 1) | ks) * 256 + lane * 4]);
#pragma unroll
            for (int mt = 0; mt < 4; ++mt)
#pragma unroll
                for (int nt = 0; nt < 4; ++nt)
                    acc[mt][nt] = __builtin_amdgcn_mfma_f32_16x16x32_bf16(
                        af[mt], bfr[nt], acc[mt][nt], 0, 0, 0);
        }
        __syncthreads();
    }

    // epilogue: C/D layout col = lane&15, row = (lane>>4)*4 + reg  [m89/m91]
    const int colc = lane & 15, qr = lane >> 4;
#pragma unroll
    for (int mt = 0; mt < 4; ++mt) {
#pragma unroll
        for (int nt = 0; nt < 4; ++nt) {
            int row0 = m_blk * 128 + (wm * 4 + mt) * 16 + qr * 4;
            int c    = n_blk * 128 + (wn * 4 + nt) * 16 + colc;
#pragma unroll
            for (int i = 0; i < 4; ++i)
                out[(size_t)(row0 + i) * N_DIM + c] = acc[mt][nt][i];
        }
    }
}

// ---------------- Fallback: round-1 fused kernel (used only if ws too small) ----------------
__global__ __launch_bounds__(256, 2)
void qgemm_fused(const float* __restrict__ x, const int* __restrict__ Wq,
                 const float* __restrict__ scales, const float* __restrict__ zeros,
                 float* __restrict__ out) {
    __shared__ uint32_t As[4096];
    __shared__ uint32_t Bs[4096];

    const int tid  = threadIdx.x;
    const int lane = tid & 63;
    const int wv   = tid >> 6;
    const int wm   = wv >> 1, wn = wv & 1;
    const int m0 = blockIdx.x * 128;
    const int n0 = blockIdx.y * 128;
    const int bc  = tid & 127;
    const int brh = tid >> 7;

    int a_row[4], a_col[4], a_dst[4];
#pragma unroll
    for (int j = 0; j < 4; ++j) {
        int sl  = tid + 256 * j;
        int blk = sl >> 6;
        int ln  = sl & 63;
        int mt  = blk >> 1, ks = blk & 1;
        a_row[j] = m0 + mt * 16 + (ln & 15);
        a_col[j] = ks * 32 + (ln >> 4) * 8;
        a_dst[j] = blk * 256 + ln * 4;
    }

    f32x4 acc[4][4];
#pragma unroll
    for (int mt = 0; mt < 4; ++mt)
#pragma unroll
        for (int nt = 0; nt < 4; ++nt)
            acc[mt][nt] = (f32x4){0.f, 0.f, 0.f, 0.f};

    float4   pa[4][2];
    uint32_t pw[4];
    float    s_raw, z_raw;
#pragma unroll
    for (int j = 0; j < 4; ++j) {
        const float4* p = reinterpret_cast<const float4*>(
            x + (size_t)a_row[j] * K_DIM + a_col[j]);
        pa[j][0] = p[0];
        pa[j][1] = p[1];
    }
#pragma unroll
    for (int j = 0; j < 4; ++j) {
        int r = brh * 4 + j;
        pw[j] = (uint32_t)Wq[(size_t)r * N_DIM + n0 + bc];
    }
    s_raw = scales[n0 + bc];
    z_raw = zeros[n0 + bc];

    float sv = 0.f, bv = 0.f;

    for (int kk = 0; kk < K_DIM; kk += 64) {
        if ((kk & 127) == 0) {
            sv = s_raw;
            bv = -(128.0f + z_raw) * s_raw;
        }
#pragma unroll
        for (int j = 0; j < 4; ++j) {
            uint4 o;
            o.x = pack2_bf16(pa[j][0].x, pa[j][0].y);
            o.y = pack2_bf16(pa[j][0].z, pa[j][0].w);
            o.z = pack2_bf16(pa[j][1].x, pa[j][1].y);
            o.w = pack2_bf16(pa[j][1].z, pa[j][1].w);
            *reinterpret_cast<uint4*>(&As[a_dst[j]]) = o;
        }
#pragma unroll
        for (int j = 0; j < 4; ++j) {
            int r  = brh * 4 + j;
            uint4 o = dequant_word(pw[j], sv, bv);
            int ks  = r >> 2, q = r & 3;
            int blk = ((bc >> 4) << 1) | ks;
            *reinterpret_cast<uint4*>(&Bs[blk * 256 + (q * 16 + (bc & 15)) * 4]) = o;
        }
        __syncthreads();

        int kn = kk + 64;
        if (kn < K_DIM) {
#pragma unroll
            for (int j = 0; j < 4; ++j) {
                const float4* p = reinterpret_cast<const float4*>(
                    x + (size_t)a_row[j] * K_DIM + kn + a_col[j]);
                pa[j][0] = p[0];
                pa[j][1] = p[1];
            }
            int kp0 = kn >> 3;
#pragma unroll
            for (int j = 0; j < 4; ++j) {
                int r = brh * 4 + j;
                pw[j] = (uint32_t)Wq[(size_t)(kp0 + r) * N_DIM + n0 + bc];
            }
            if ((kn & 127) == 0) {
                int g = kn >> 7;
                s_raw = scales[(size_t)g * N_DIM + n0 + bc];
                z_raw = zeros[(size_t)g * N_DIM + n0 + bc];
            }
        }

#pragma unroll
        for (int ks = 0; ks < 2; ++ks) {
            bf16x8 af[4], bfr[4];
#pragma unroll
            for (int mt = 0; mt < 4; ++mt)
                af[mt] = *reinterpret_cast<const bf16x8*>(
                    &As[(((wm * 4 + mt) << 1) | ks) * 256 + lane * 4]);
#pragma unroll
            for (int nt = 0; nt < 4; ++nt)
                bfr[nt] = *reinterpret_cast<const bf16x8*>(
                    &Bs[(((wn * 4 + nt) << 1) | ks) * 256 + lane * 4]);
#pragma unroll
            for (int mt = 0; mt < 4; ++mt)
#pragma unroll
                for (int nt = 0; nt < 4; ++nt)
                    acc[mt][nt] = __builtin_amdgcn_mfma_f32_16x16x32_bf16(
                        af[mt], bfr[nt], acc[mt][nt], 0, 0, 0);
        }
        __syncthreads();
    }

    const int colc = lane & 15, qr = lane >> 4;
#pragma unroll
    for (int mt = 0; mt < 4; ++mt) {
#pragma unroll
        for (int nt = 0; nt < 4; ++nt) {
            int row0 = m0 + (wm * 4 + mt) * 16 + qr * 4;
            int c    = n0 + (wn * 4 + nt) * 16 + colc;
#pragma unroll
            for (int i = 0; i < 4; ++i)
                out[(size_t)(row0 + i) * N_DIM + c] = acc[mt][nt][i];
        }
    }
}

extern "C" void kernel_launch(void* const* d_in, const int* in_sizes, int n_in,
                              void* d_out, int out_size, void* d_ws, size_t ws_size,
                              hipStream_t stream) {
    const float* x      = (const float*)d_in[0];
    const int*   Wq     = (const int*)d_in[1];
    const float* scales = (const float*)d_in[2];
    const float* zeros  = (const float*)d_in[3];
    float*       out    = (float*)d_out;

    if (ws_size >= WS_NEEDED) {
        uint32_t* Apre = (uint32_t*)d_ws;
        uint32_t* Bpre = (uint32_t*)((char*)d_ws + A_PRE_BYTES);
        conv_x<<<dim3(512, 4), dim3(256), 0, stream>>>(x, Apre);
        dequant_w<<<dim3(43, 128), dim3(256), 0, stream>>>(Wq, scales, zeros, Bpre);
        gemm_pre<<<dim3(M_DIM / 128, N_DIM / 128), dim3(256), 0, stream>>>(Apre, Bpre, out);
    } else {
        qgemm_fused<<<dim3(M_DIM / 128, N_DIM / 128), dim3(256), 0, stream>>>(
            x, Wq, scales, zeros, out);
    }
}